// Round 7
// baseline (271.474 us; speedup 1.0000x reference)
//
#include <hip/hip_runtime.h>
#include <math.h>
#include <stdint.h>

#define P_TOT 8192
#define CDIM  256
#define KC    50
#define NPIX  1024
#define TI    32

// MFMA pass geometry: 256-thread blocks, 4 waves x 32 rows = 128 rows/block
#define RPB   128
#define JSPA  32                 // j-splits for pass1
#define JCHA  (P_TOT / JSPA)     // 256
#define JSP   16                 // j-splits for pass2
#define JCH   (P_TOT / JSP)      // 512
#define JST   32
#define NJS   (JCH / JST)        // 16
#define NJSA  (JCHA / JST)       // 8

// sK swizzle: row-pair XOR
#define SWZK(row) ((((row) >> 1) & 7) << 4)

// workspace float offsets
#define OFF_NRM   0         // [8192]
#define OFF_Z     8192      // [8192]
#define OFF_S2    16384     // [8192]
#define OFF_THR   24576     // [8192]
#define OFF_DEN   32768     // [8192]
#define OFF_SCAL  40960     // [64] 0=sum_d_nor 1=sum_d_ano
#define OFF_C2    41024     // [64]
#define OFF_NFLAG 53888     // [8192] 1.0 if normal else 0.0
#define OFF_XNB   65536     // [8192][256] bf16 normalized (1M floats)
#define OFF_XTB   1114112   // [256][8192] bf16 raw X^T    (1M floats)
#define OFF_PART  65536     // [4][51][8192] f32 partials (aliases XNB/XTB, used before k2)
#define OFF_OUT   2162688   // [8192][256] f32 numerator accum
#define IOFF_BASE 4259840
#define II_ANOIDX 0
#define II_M      8192
#define II_CNTANO 8193
#define II_FLAGS  8200

typedef __attribute__((ext_vector_type(8))) short short8;
typedef __attribute__((ext_vector_type(4))) float f32x4;

__device__ __forceinline__ ushort f2bf(float x) {
    union { float f; unsigned u; } v; v.f = x;
    unsigned r = v.u + 0x7fffu + ((v.u >> 16) & 1u);
    return (ushort)(r >> 16);
}

typedef const __attribute__((address_space(1))) void gas_void;
typedef __attribute__((address_space(3))) void las_void;
__device__ __forceinline__ void gld_lds16(const void* g, void* l) {
    __builtin_amdgcn_global_load_lds(
        (gas_void*)(unsigned long long)(uintptr_t)g,
        (las_void*)(unsigned int)(uintptr_t)l, 16, 0, 0);
}

__global__ void k0_prep(const float* __restrict__ center, float* __restrict__ wsF) {
    int tid = threadIdx.x;
    if (tid >= 200) return;
    int k = tid >> 2, q = tid & 3;
    float s = 0.f;
    const float* cp = center + k * CDIM + q * 64;
    for (int c = 0; c < 64; ++c) { float v = cp[c]; s += v * v; }
    s += __shfl_down(s, 2);
    s += __shfl_down(s, 1);
    if (q == 0) wsF[OFF_C2 + k] = s;
}

__global__ __launch_bounds__(256) void k1a_dot(const float* __restrict__ f,
                                               const float* __restrict__ center,
                                               float* __restrict__ PART) {
    int tid = threadIdx.x;
    int px = blockIdx.x * 256 + tid;
    int cg = blockIdx.y;
    int b = px >> 10, n = px & 1023;
    const float* fp = f + ((size_t)b * CDIM + cg * 64) * NPIX + n;
    float acc[KC];
#pragma unroll
    for (int k = 0; k < KC; ++k) acc[k] = 0.f;
    float x2 = 0.f;
    for (int cc = 0; cc < 64; ++cc) {
        float xv = fp[(size_t)cc * NPIX];
        x2 += xv * xv;
        const float* cp = center + (cg * 64 + cc);
#pragma unroll
        for (int k = 0; k < KC; ++k) acc[k] = fmaf(xv, cp[(size_t)k * CDIM], acc[k]);
    }
    float* dst = PART + (size_t)cg * 51 * P_TOT + px;
#pragma unroll
    for (int k = 0; k < KC; ++k) dst[(size_t)k * P_TOT] = acc[k];
    dst[(size_t)50 * P_TOT] = x2;
}

__global__ __launch_bounds__(256) void k1b_min(const float* __restrict__ TcP,
                                               const float* __restrict__ c2g,
                                               const float* __restrict__ PART,
                                               float* __restrict__ wsF,
                                               int* __restrict__ wsI) {
    int tid = threadIdx.x;
    int px = blockIdx.x * 256 + tid;
    float x2 = 0.f;
#pragma unroll
    for (int g = 0; g < 4; ++g) x2 += PART[((size_t)g * 51 + 50) * P_TOT + px];
    float d2m = 3.4e38f;
#pragma unroll 10
    for (int k = 0; k < KC; ++k) {
        float s = PART[(size_t)k * P_TOT + px];
#pragma unroll
        for (int g = 1; g < 4; ++g) s += PART[((size_t)g * 51 + k) * P_TOT + px];
        float d2 = x2 + c2g[k] - 2.f * s;
        d2m = fminf(d2m, d2);
    }
    float d = sqrtf(fmaxf(d2m, 0.f));
    bool ano = d > TcP[0];
    wsF[OFF_NRM + px] = fmaxf(sqrtf(x2), 1e-8f);
    wsF[OFF_NFLAG + px] = ano ? 0.f : 1.f;
    wsI[II_FLAGS + px] = ano ? 1 : 0;

    float dn = ano ? 0.f : d;
    float da = ano ? d : 0.f;
    for (int o = 32; o >= 1; o >>= 1) { dn += __shfl_down(dn, o); da += __shfl_down(da, o); }
    int lane = tid & 63;
    unsigned long long mask = __ballot(ano);
    int cnt = __popcll(mask);
    if (lane == 0) {
        atomicAdd(&wsF[OFF_SCAL + 0], dn);
        atomicAdd(&wsF[OFF_SCAL + 1], da);
        if (cnt) atomicAdd(&wsI[II_CNTANO], cnt);
    }
    if (ano) {
        int leader = __ffsll((unsigned long long)mask) - 1;
        int base = 0;
        if (lane == leader) base = atomicAdd(&wsI[II_M], cnt);
        base = __shfl(base, leader);
        int off = __popcll(mask & ((1ull << lane) - 1ull));
        wsI[II_ANOIDX + base + off] = px;
    }
}

__global__ void k2_convert(const float* __restrict__ f, float* __restrict__ wsF) {
    __shared__ float t[32][33];
    int b = blockIdx.z, n0 = blockIdx.x * 32, c0 = blockIdx.y * 32;
    int tx = threadIdx.x, ty = threadIdx.y;
    const float* src = f + ((size_t)b * CDIM + c0) * NPIX + n0;
    ushort* XnB = (ushort*)(wsF + OFF_XNB);
    ushort* XTB = (ushort*)(wsF + OFF_XTB);
#pragma unroll
    for (int r = 0; r < 32; r += 8) {
        float v = src[(size_t)(ty + r) * NPIX + tx];
        t[ty + r][tx] = v;
        XTB[(size_t)(c0 + ty + r) * P_TOT + b * NPIX + n0 + tx] = f2bf(v);
    }
    __syncthreads();
#pragma unroll
    for (int r = 0; r < 32; r += 8) {
        int p = b * NPIX + n0 + ty + r;
        float nrm = wsF[OFF_NRM + p];
        XnB[(size_t)p * CDIM + c0 + tx] = f2bf(t[tx][ty + r] / nrm);
    }
}

__global__ void k3_copy(const float* __restrict__ f, float* __restrict__ out,
                        const float* __restrict__ wsF, const int* __restrict__ wsI) {
    int gid = blockIdx.x * blockDim.x + threadIdx.x;
    const float4* src = (const float4*)f;
    float4* dst = (float4*)out;
    int total = P_TOT * CDIM / 4;
    for (int i = gid; i < total; i += gridDim.x * blockDim.x) dst[i] = src[i];
    if (gid == 0) {
        int cntAno = wsI[II_CNTANO];
        float cntNor = (float)(P_TOT - cntAno);
        float meanNor = wsF[OFF_SCAL + 0] / fmaxf(cntNor, 1.f);
        float meanAno = wsF[OFF_SCAL + 1] / fmaxf((float)cntAno, 1.f);
        out[P_TOT * CDIM] = (cntAno > 0) ? meanNor / (meanAno + 0.001f) : meanNor;
    }
}

// pass1: Z = sum_nor exp(s-1), S2 = sum exp^2; 4 waves x 32 rows, dbuf DMA
__global__ __launch_bounds__(256, 4) void k5a(float* __restrict__ wsF, const int* __restrict__ wsI) {
    const int Mv = wsI[II_M];
    const int i0 = blockIdx.x * RPB;
    if (i0 >= Mv) return;
    __shared__ __align__(16) ushort sK[2][JST * CDIM];   // 2 x 16KB
    const int tid = threadIdx.x;
    const int wave = tid >> 6, lane = tid & 63;
    const int lrow = lane & 15, lgrp = lane >> 4;
    const char* XnBb = (const char*)(wsF + OFF_XNB);
    const float* nflag = wsF + OFF_NFLAG;
    const int* anoIdx = wsI + II_ANOIDX;
    const int jc0 = blockIdx.y * JCHA;
    const int iw = i0 + wave * 32;

    short8 qf[2][8];
#pragma unroll
    for (int ag = 0; ag < 2; ++ag) {
        int arow = anoIdx[min(iw + ag * 16 + lrow, Mv - 1)];
        const ushort* qp = (const ushort*)XnBb + (size_t)arow * CDIM + lgrp * 8;
#pragma unroll
        for (int kc = 0; kc < 8; ++kc) qf[ag][kc] = *(const short8*)(qp + kc * 32);
    }
    float zAcc[2][4], s2Acc[2][4];
#pragma unroll
    for (int ag = 0; ag < 2; ++ag)
#pragma unroll
        for (int r = 0; r < 4; ++r) { zAcc[ag][r] = 0.f; s2Acc[ag][r] = 0.f; }

    auto stageK = [&](int buf, int j0) {
#pragma unroll
        for (int it = 0; it < 4; ++it) {
            int chunk = (wave << 2) + it;
            int d = (chunk << 10) + (lane << 4);
            int row = d >> 9;
            int srco = (d & ~511) | ((d & 511) ^ SWZK(row));
            gld_lds16(XnBb + ((size_t)j0 << 9) + srco, (char*)sK[buf] + (chunk << 10));
        }
    };

    stageK(0, jc0);
    __syncthreads();
    int cur = 0;
    for (int js = 0; js < NJSA; ++js) {
        int j0 = jc0 + js * JST;
        if (js + 1 < NJSA) stageK(cur ^ 1, j0 + JST);
        float mf0 = nflag[j0 + lrow];
        float mf1 = nflag[j0 + 16 + lrow];
        f32x4 acc[2][2];
#pragma unroll
        for (int ag = 0; ag < 2; ++ag)
#pragma unroll
            for (int jt = 0; jt < 2; ++jt) acc[ag][jt] = (f32x4){0.f, 0.f, 0.f, 0.f};
#pragma unroll
        for (int kc = 0; kc < 8; ++kc) {
            int cb = (kc << 6) + (lgrp << 4);
            int b0 = lrow * 512 + (cb ^ SWZK(lrow));
            int b1 = (16 + lrow) * 512 + (cb ^ SWZK(16 + lrow));
            short8 bf0 = *(const short8*)((const char*)sK[cur] + b0);
            short8 bf1 = *(const short8*)((const char*)sK[cur] + b1);
            acc[0][0] = __builtin_amdgcn_mfma_f32_16x16x32_bf16(qf[0][kc], bf0, acc[0][0], 0, 0, 0);
            acc[0][1] = __builtin_amdgcn_mfma_f32_16x16x32_bf16(qf[0][kc], bf1, acc[0][1], 0, 0, 0);
            acc[1][0] = __builtin_amdgcn_mfma_f32_16x16x32_bf16(qf[1][kc], bf0, acc[1][0], 0, 0, 0);
            acc[1][1] = __builtin_amdgcn_mfma_f32_16x16x32_bf16(qf[1][kc], bf1, acc[1][1], 0, 0, 0);
        }
#pragma unroll
        for (int ag = 0; ag < 2; ++ag)
#pragma unroll
            for (int r = 0; r < 4; ++r) {
                float e0 = __expf(acc[ag][0][r] - 1.f) * mf0;
                float e1 = __expf(acc[ag][1][r] - 1.f) * mf1;
                zAcc[ag][r] += e0 + e1;
                s2Acc[ag][r] += e0 * e0 + e1 * e1;
            }
        __syncthreads();
        cur ^= 1;
    }
#pragma unroll
    for (int ag = 0; ag < 2; ++ag)
#pragma unroll
        for (int r = 0; r < 4; ++r) {
            float z = zAcc[ag][r], q = s2Acc[ag][r];
            for (int m = 8; m >= 1; m >>= 1) { z += __shfl_xor(z, m); q += __shfl_xor(q, m); }
            if (lrow == 0) {
                int i = iw + ag * 16 + lgrp * 4 + r;
                if (i < Mv) { atomicAdd(&wsF[OFF_Z + i], z); atomicAdd(&wsF[OFF_S2 + i], q); }
            }
        }
}

__global__ void k4b_thr(float* __restrict__ wsF, const int* __restrict__ wsI) {
    int Mv = wsI[II_M];
    int idx = blockIdx.x * 256 + threadIdx.x;
    if (idx >= Mv) return;
    float t = fmaxf((float)(P_TOT - wsI[II_CNTANO]), 1.f);
    float Z = wsF[OFF_Z + idx], S2 = wsF[OFF_S2 + idx];
    float mu = 1.f / t;
    float var = S2 / (Z * Z * t) - mu * mu;
    wsF[OFF_THR + idx] = mu - 2.f * sqrtf(fmaxf(var, 0.f));
}

// pass2: sim -> sw (select) -> (sw @ X); 4 waves x 32 rows, 2 A-frags per wave
__global__ __launch_bounds__(256, 2) void k5c(float* __restrict__ wsF, const int* __restrict__ wsI) {
    const int Mv = wsI[II_M];
    const int i0 = blockIdx.x * RPB;
    if (i0 >= Mv) return;
    __shared__ __align__(16) ushort sK[2][JST * CDIM];    // 2 x 16KB
    __shared__ __align__(16) ushort sXT[2][CDIM * JST];   // 2 x 16KB paired-row layout
    __shared__ __align__(16) char sSW[4][32 * 72];        // per-wave [32 i][32 j]x2B, 72B stride
    const int tid = threadIdx.x;
    const int wave = tid >> 6, lane = tid & 63;
    const int lrow = lane & 15, lgrp = lane >> 4;
    const char* XnBb = (const char*)(wsF + OFF_XNB);
    const char* XTBb = (const char*)(wsF + OFF_XTB);
    const float* nflag = wsF + OFF_NFLAG;
    const int* anoIdx = wsI + II_ANOIDX;
    const int jc0 = blockIdx.y * JCH;
    const int iw = i0 + wave * 32;

    short8 qf[2][8];
#pragma unroll
    for (int ag = 0; ag < 2; ++ag) {
        int arow = anoIdx[min(iw + ag * 16 + lrow, Mv - 1)];
        const ushort* qp = (const ushort*)XnBb + (size_t)arow * CDIM + lgrp * 8;
#pragma unroll
        for (int kc = 0; kc < 8; ++kc) qf[ag][kc] = *(const short8*)(qp + kc * 32);
    }
    float rz[2][4], thr[2][4], den[2][4];
#pragma unroll
    for (int ag = 0; ag < 2; ++ag)
#pragma unroll
        for (int r = 0; r < 4; ++r) {
            int i = min(iw + ag * 16 + lgrp * 4 + r, Mv - 1);
            rz[ag][r] = 1.f / wsF[OFF_Z + i];
            thr[ag][r] = wsF[OFF_THR + i];
            den[ag][r] = 0.f;
        }
    f32x4 oAcc[2][16];
#pragma unroll
    for (int ag = 0; ag < 2; ++ag)
#pragma unroll
        for (int ct = 0; ct < 16; ++ct) oAcc[ag][ct] = (f32x4){0.f, 0.f, 0.f, 0.f};

    auto stageK = [&](int buf, int j0) {
#pragma unroll
        for (int it = 0; it < 4; ++it) {
            int chunk = (wave << 2) + it;
            int d = (chunk << 10) + (lane << 4);
            int row = d >> 9;
            int srco = (d & ~511) | ((d & 511) ^ SWZK(row));
            gld_lds16(XnBb + ((size_t)j0 << 9) + srco, (char*)sK[buf] + (chunk << 10));
        }
    };
    auto stageX = [&](int buf, int j0) {
#pragma unroll
        for (int it = 0; it < 4; ++it) {
            int chunk = (wave << 2) + it;
            int d = (chunk << 10) + (lane << 4);
            int R = d >> 7;
            int q = (d & 127) ^ ((R & 7) << 4);
            int c = 2 * R + (q >> 6);
            gld_lds16(XTBb + (size_t)c * (P_TOT * 2) + ((size_t)j0 << 1) + (q & 63),
                      (char*)sXT[buf] + (chunk << 10));
        }
    };

    stageK(0, jc0);
    stageX(0, jc0);
    __syncthreads();
    int cur = 0;
    char* msw = sSW[wave];
    for (int js = 0; js < NJS; ++js) {
        int j0 = jc0 + js * JST;
        if (js + 1 < NJS) { stageK(cur ^ 1, j0 + JST); stageX(cur ^ 1, j0 + JST); }
        float2 mfp = *(const float2*)&nflag[j0 + 2 * lrow];
        f32x4 acc[2][2];
#pragma unroll
        for (int ag = 0; ag < 2; ++ag)
#pragma unroll
            for (int jt = 0; jt < 2; ++jt) acc[ag][jt] = (f32x4){0.f, 0.f, 0.f, 0.f};
#pragma unroll
        for (int kc = 0; kc < 8; ++kc) {
            int cb = (kc << 6) + (lgrp << 4);
            int b0 = (2 * lrow) * 512 + (cb ^ SWZK(2 * lrow));
            int b1 = (2 * lrow + 1) * 512 + (cb ^ SWZK(2 * lrow + 1));
            short8 bf0 = *(const short8*)((const char*)sK[cur] + b0);
            short8 bf1 = *(const short8*)((const char*)sK[cur] + b1);
            acc[0][0] = __builtin_amdgcn_mfma_f32_16x16x32_bf16(qf[0][kc], bf0, acc[0][0], 0, 0, 0);
            acc[0][1] = __builtin_amdgcn_mfma_f32_16x16x32_bf16(qf[0][kc], bf1, acc[0][1], 0, 0, 0);
            acc[1][0] = __builtin_amdgcn_mfma_f32_16x16x32_bf16(qf[1][kc], bf0, acc[1][0], 0, 0, 0);
            acc[1][1] = __builtin_amdgcn_mfma_f32_16x16x32_bf16(qf[1][kc], bf1, acc[1][1], 0, 0, 0);
        }
        // sw = (w > thr) ? w : 0; acc[ag][0] -> j=j0+2*lrow, acc[ag][1] -> j0+2*lrow+1
#pragma unroll
        for (int ag = 0; ag < 2; ++ag)
#pragma unroll
            for (int r = 0; r < 4; ++r) {
                int irow = ag * 16 + lgrp * 4 + r;
                float w0 = __expf(acc[ag][0][r] - 1.f) * mfp.x * rz[ag][r];
                float w1 = __expf(acc[ag][1][r] - 1.f) * mfp.y * rz[ag][r];
                float sw0 = (w0 > thr[ag][r]) ? w0 : 0.f;
                float sw1 = (w1 > thr[ag][r]) ? w1 : 0.f;
                den[ag][r] += sw0 + sw1;
                *(unsigned*)(msw + irow * 72 + 4 * lrow) =
                    ((unsigned)f2bf(sw1) << 16) | (unsigned)f2bf(sw0);
            }
        short8 aF0 = *(const short8*)(msw + lrow * 72 + lgrp * 16);
        short8 aF1 = *(const short8*)(msw + (16 + lrow) * 72 + lgrp * 16);
#pragma unroll
        for (int ct = 0; ct < 16; ++ct) {
            int crow = ct * 16 + lrow;
            int R = crow >> 1;
            int off = (((crow & 1) << 6) + (lgrp << 4)) ^ ((R & 7) << 4);
            short8 bf = *(const short8*)((const char*)sXT[cur] + R * 128 + off);
            oAcc[0][ct] = __builtin_amdgcn_mfma_f32_16x16x32_bf16(aF0, bf, oAcc[0][ct], 0, 0, 0);
            oAcc[1][ct] = __builtin_amdgcn_mfma_f32_16x16x32_bf16(aF1, bf, oAcc[1][ct], 0, 0, 0);
        }
        __syncthreads();
        cur ^= 1;
    }

#pragma unroll
    for (int ag = 0; ag < 2; ++ag)
#pragma unroll
        for (int r = 0; r < 4; ++r) {
            float dv = den[ag][r];
            for (int m = 8; m >= 1; m >>= 1) dv += __shfl_xor(dv, m);
            int i = iw + ag * 16 + lgrp * 4 + r;
            if (lrow == 0 && i < Mv) atomicAdd(&wsF[OFF_DEN + i], dv);
            if (i < Mv) {
                float* go = wsF + OFF_OUT + (size_t)i * CDIM + lrow;
#pragma unroll
                for (int ct = 0; ct < 16; ++ct) atomicAdd(&go[ct * 16], oAcc[ag][ct][r]);
            }
        }
}

__global__ void k4d_final(float* __restrict__ out, const float* __restrict__ wsF,
                          const int* __restrict__ wsI) {
    int Mv = wsI[II_M];
    int i0 = blockIdx.x * TI;
    if (i0 >= Mv) return;
    int tid = threadIdx.x;
    int ii = tid >> 3, cg = tid & 7;
    int i = i0 + ii;
    if (i >= Mv) return;
    int p = wsI[II_ANOIDX + i];
    int b = p >> 10, n = p & 1023;
    float rden = 1.f / wsF[OFF_DEN + i];
    const float* go = wsF + OFF_OUT + (size_t)i * CDIM;
    float* op = out + (size_t)b * CDIM * NPIX + n;
#pragma unroll
    for (int cc = 0; cc < 32; ++cc) {
        int c = cc * 8 + cg;
        op[(size_t)c * NPIX] = go[c] * rden;
    }
}

extern "C" void kernel_launch(void* const* d_in, const int* in_sizes, int n_in,
                              void* d_out, int out_size, void* d_ws, size_t ws_size,
                              hipStream_t stream) {
    const float* f = (const float*)d_in[0];
    const float* center = (const float*)d_in[1];
    const float* Tc = (const float*)d_in[2];
    float* out = (float*)d_out;
    float* wsF = (float*)d_ws;
    int* wsI = (int*)(wsF + IOFF_BASE);

    hipMemsetAsync(wsF + OFF_Z, 0, (OFF_C2 + 64 - OFF_Z) * sizeof(float), stream);
    hipMemsetAsync(wsF + OFF_OUT, 0, (size_t)P_TOT * CDIM * sizeof(float), stream);
    hipMemsetAsync(wsI + II_M, 0, 2 * sizeof(int), stream);

    k0_prep<<<1, 256, 0, stream>>>(center, wsF);
    dim3 g1a(32, 4);
    k1a_dot<<<g1a, 256, 0, stream>>>(f, center, wsF + OFF_PART);
    k1b_min<<<32, 256, 0, stream>>>(Tc, wsF + OFF_C2, wsF + OFF_PART, wsF, wsI);
    dim3 g2(32, 8, 8), b2(32, 8);
    k2_convert<<<g2, b2, 0, stream>>>(f, wsF);
    k3_copy<<<512, 256, 0, stream>>>(f, out, wsF, wsI);
    dim3 g5a(P_TOT / RPB, JSPA);
    k5a<<<g5a, 256, 0, stream>>>(wsF, wsI);
    k4b_thr<<<P_TOT / 256, 256, 0, stream>>>(wsF, wsI);
    dim3 g5c(P_TOT / RPB, JSP);
    k5c<<<g5c, 256, 0, stream>>>(wsF, wsI);
    k4d_final<<<P_TOT / TI, 256, 0, stream>>>(out, wsF, wsI);
}

// Round 8
// 195.640 us; speedup vs baseline: 1.3876x; 1.3876x over previous
//
#include <hip/hip_runtime.h>
#include <math.h>
#include <stdint.h>

#define P_TOT 8192
#define CDIM  256
#define KC    50
#define NPIX  1024
#define TI    32

// k5a: 4 waves x 32 rows = 128 rows/block
#define RPBA  128
#define JSPA  32
#define JCHA  (P_TOT / JSPA)     // 256
#define NJSA  (JCHA / 32)        // 8
// k5c: 2 pairs x 32 rows = 64 rows/block, pair waves split c-dim
#define RPBC  64
#define JSP   8
#define JCH   (P_TOT / JSP)      // 1024
#define NJS   (JCH / 32)         // 32

#define SWZ8(r) (((r) & 7) << 4)

// workspace float offsets
#define OFF_NRM   0
#define OFF_Z     8192
#define OFF_S2    16384
#define OFF_THR   24576
#define OFF_DEN   32768
#define OFF_SCAL  40960
#define OFF_C2    41024
#define OFF_NFLAG 53888
#define OFF_XNB   65536     // [8192][256] bf16 normalized
#define OFF_XTB   1114112   // [256][8192] bf16 raw X^T
#define OFF_PART  65536     // aliases XNB/XTB (pre-k2 only)
#define OFF_OUT   2162688   // [8192][256] f32 numerator
#define IOFF_BASE 4259840
#define II_ANOIDX 0
#define II_M      8192
#define II_CNTANO 8193
#define II_FLAGS  8200

typedef __attribute__((ext_vector_type(8))) short short8;
typedef __attribute__((ext_vector_type(16))) float f32x16;

__device__ __forceinline__ ushort f2bf(float x) {
    union { float f; unsigned u; } v; v.f = x;
    unsigned r = v.u + 0x7fffu + ((v.u >> 16) & 1u);
    return (ushort)(r >> 16);
}

typedef const __attribute__((address_space(1))) void gas_void;
typedef __attribute__((address_space(3))) void las_void;
__device__ __forceinline__ void gld_lds16(const void* g, void* l) {
    __builtin_amdgcn_global_load_lds(
        (gas_void*)(unsigned long long)(uintptr_t)g,
        (las_void*)(unsigned int)(uintptr_t)l, 16, 0, 0);
}

__global__ void k0_prep(const float* __restrict__ center, float* __restrict__ wsF) {
    int tid = threadIdx.x;
    if (tid >= 200) return;
    int k = tid >> 2, q = tid & 3;
    float s = 0.f;
    const float* cp = center + k * CDIM + q * 64;
    for (int c = 0; c < 64; ++c) { float v = cp[c]; s += v * v; }
    s += __shfl_down(s, 2);
    s += __shfl_down(s, 1);
    if (q == 0) wsF[OFF_C2 + k] = s;
}

__global__ __launch_bounds__(256) void k1a_dot(const float* __restrict__ f,
                                               const float* __restrict__ center,
                                               float* __restrict__ PART) {
    int tid = threadIdx.x;
    int px = blockIdx.x * 256 + tid;
    int cg = blockIdx.y;
    int b = px >> 10, n = px & 1023;
    const float* fp = f + ((size_t)b * CDIM + cg * 64) * NPIX + n;
    float acc[KC];
#pragma unroll
    for (int k = 0; k < KC; ++k) acc[k] = 0.f;
    float x2 = 0.f;
    for (int cc = 0; cc < 64; ++cc) {
        float xv = fp[(size_t)cc * NPIX];
        x2 += xv * xv;
        const float* cp = center + (cg * 64 + cc);
#pragma unroll
        for (int k = 0; k < KC; ++k) acc[k] = fmaf(xv, cp[(size_t)k * CDIM], acc[k]);
    }
    float* dst = PART + (size_t)cg * 51 * P_TOT + px;
#pragma unroll
    for (int k = 0; k < KC; ++k) dst[(size_t)k * P_TOT] = acc[k];
    dst[(size_t)50 * P_TOT] = x2;
}

__global__ __launch_bounds__(256) void k1b_min(const float* __restrict__ TcP,
                                               const float* __restrict__ c2g,
                                               const float* __restrict__ PART,
                                               float* __restrict__ wsF,
                                               int* __restrict__ wsI) {
    int tid = threadIdx.x;
    int px = blockIdx.x * 256 + tid;
    float x2 = 0.f;
#pragma unroll
    for (int g = 0; g < 4; ++g) x2 += PART[((size_t)g * 51 + 50) * P_TOT + px];
    float d2m = 3.4e38f;
#pragma unroll 10
    for (int k = 0; k < KC; ++k) {
        float s = PART[(size_t)k * P_TOT + px];
#pragma unroll
        for (int g = 1; g < 4; ++g) s += PART[((size_t)g * 51 + k) * P_TOT + px];
        float d2 = x2 + c2g[k] - 2.f * s;
        d2m = fminf(d2m, d2);
    }
    float d = sqrtf(fmaxf(d2m, 0.f));
    bool ano = d > TcP[0];
    wsF[OFF_NRM + px] = fmaxf(sqrtf(x2), 1e-8f);
    wsF[OFF_NFLAG + px] = ano ? 0.f : 1.f;
    wsI[II_FLAGS + px] = ano ? 1 : 0;

    float dn = ano ? 0.f : d;
    float da = ano ? d : 0.f;
    for (int o = 32; o >= 1; o >>= 1) { dn += __shfl_down(dn, o); da += __shfl_down(da, o); }
    int lane = tid & 63;
    unsigned long long mask = __ballot(ano);
    int cnt = __popcll(mask);
    if (lane == 0) {
        atomicAdd(&wsF[OFF_SCAL + 0], dn);
        atomicAdd(&wsF[OFF_SCAL + 1], da);
        if (cnt) atomicAdd(&wsI[II_CNTANO], cnt);
    }
    if (ano) {
        int leader = __ffsll((unsigned long long)mask) - 1;
        int base = 0;
        if (lane == leader) base = atomicAdd(&wsI[II_M], cnt);
        base = __shfl(base, leader);
        int off = __popcll(mask & ((1ull << lane) - 1ull));
        wsI[II_ANOIDX + base + off] = px;
    }
}

__global__ void k2_convert(const float* __restrict__ f, float* __restrict__ wsF) {
    __shared__ float t[32][33];
    int b = blockIdx.z, n0 = blockIdx.x * 32, c0 = blockIdx.y * 32;
    int tx = threadIdx.x, ty = threadIdx.y;
    const float* src = f + ((size_t)b * CDIM + c0) * NPIX + n0;
    ushort* XnB = (ushort*)(wsF + OFF_XNB);
    ushort* XTB = (ushort*)(wsF + OFF_XTB);
#pragma unroll
    for (int r = 0; r < 32; r += 8) {
        float v = src[(size_t)(ty + r) * NPIX + tx];
        t[ty + r][tx] = v;
        XTB[(size_t)(c0 + ty + r) * P_TOT + b * NPIX + n0 + tx] = f2bf(v);
    }
    __syncthreads();
#pragma unroll
    for (int r = 0; r < 32; r += 8) {
        int p = b * NPIX + n0 + ty + r;
        float nrm = wsF[OFF_NRM + p];
        XnB[(size_t)p * CDIM + c0 + tx] = f2bf(t[tx][ty + r] / nrm);
    }
}

__global__ void k3_copy(const float* __restrict__ f, float* __restrict__ out,
                        const float* __restrict__ wsF, const int* __restrict__ wsI) {
    int gid = blockIdx.x * blockDim.x + threadIdx.x;
    const float4* src = (const float4*)f;
    float4* dst = (float4*)out;
    int total = P_TOT * CDIM / 4;
    for (int i = gid; i < total; i += gridDim.x * blockDim.x) dst[i] = src[i];
    if (gid == 0) {
        int cntAno = wsI[II_CNTANO];
        float cntNor = (float)(P_TOT - cntAno);
        float meanNor = wsF[OFF_SCAL + 0] / fmaxf(cntNor, 1.f);
        float meanAno = wsF[OFF_SCAL + 1] / fmaxf((float)cntAno, 1.f);
        out[P_TOT * CDIM] = (cntAno > 0) ? meanNor / (meanAno + 0.001f) : meanNor;
    }
}

// pass1: swapped QK via 32x32x16; lane i = lane&31, per-lane Z/S2
__global__ __launch_bounds__(256, 4) void k5a(float* __restrict__ wsF, const int* __restrict__ wsI) {
    const int Mv = wsI[II_M];
    const int i0 = blockIdx.x * RPBA;
    if (i0 >= Mv) return;
    __shared__ __align__(16) ushort sK[2][32 * CDIM];   // 2 x 16KB
    const int tid = threadIdx.x;
    const int wave = tid >> 6, lane = tid & 63;
    const int jl = lane & 31, g = lane >> 5;
    const char* XnBb = (const char*)(wsF + OFF_XNB);
    const float* nflag = wsF + OFF_NFLAG;
    const int* anoIdx = wsI + II_ANOIDX;
    const int jc0 = blockIdx.y * JCHA;
    const int iw = i0 + wave * 32;
    const int myrow = iw + jl;

    short8 qf[16];
    {
        int arow = anoIdx[min(myrow, Mv - 1)];
#pragma unroll
        for (int kc = 0; kc < 16; ++kc)
            qf[kc] = *(const short8*)(XnBb + (size_t)arow * 512 + kc * 32 + g * 16);
    }
    float z = 0.f, s2 = 0.f;

    auto stageK = [&](int buf, int j0) {
#pragma unroll
        for (int it = 0; it < 4; ++it) {
            int d = ((it * 256 + tid) << 4);
            int row = d >> 9;
            int srco = (d & ~511) | ((d & 511) ^ SWZ8(row));
            gld_lds16(XnBb + ((size_t)j0 << 9) + srco, (char*)sK[buf] + d);
        }
    };

    stageK(0, jc0);
    __syncthreads();
    int cur = 0;
    for (int js = 0; js < NJSA; ++js) {
        int j0 = jc0 + js * 32;
        if (js + 1 < NJSA) stageK(cur ^ 1, j0 + 32);
        f32x16 acc;
#pragma unroll
        for (int r = 0; r < 16; ++r) acc[r] = 0.f;
#pragma unroll
        for (int kc = 0; kc < 16; ++kc) {
            int aoff = jl * 512 + ((kc * 32 + g * 16) ^ SWZ8(jl));
            short8 af = *(const short8*)((const char*)sK[cur] + aoff);
            acc = __builtin_amdgcn_mfma_f32_32x32x16_bf16(af, qf[kc], acc, 0, 0, 0);
        }
        float nf = nflag[j0 + jl];
        unsigned um = (unsigned)__ballot(nf > 0.5f);
#pragma unroll
        for (int r = 0; r < 16; ++r) {
            int jr = (r & 3) + 8 * (r >> 2) + 4 * g;
            float e = ((um >> jr) & 1u) ? __expf(acc[r] - 1.f) : 0.f;
            z += e; s2 += e * e;
        }
        __syncthreads();
        cur ^= 1;
    }
    z += __shfl_xor(z, 32);
    s2 += __shfl_xor(s2, 32);
    if (lane < 32 && myrow < Mv) {
        atomicAdd(&wsF[OFF_Z + myrow], z);
        atomicAdd(&wsF[OFF_S2 + myrow], s2);
    }
}

__global__ void k4b_thr(float* __restrict__ wsF, const int* __restrict__ wsI) {
    int Mv = wsI[II_M];
    int idx = blockIdx.x * 256 + threadIdx.x;
    if (idx >= Mv) return;
    float t = fmaxf((float)(P_TOT - wsI[II_CNTANO]), 1.f);
    float Z = wsF[OFF_Z + idx], S2 = wsF[OFF_S2 + idx];
    float mu = 1.f / t;
    float var = S2 / (Z * Z * t) - mu * mu;
    wsF[OFF_THR + idx] = mu - 2.f * sqrtf(fmaxf(var, 0.f));
}

// pass2: swapped QK 32x32 -> in-register sw -> shfl-exchange -> PV 32x32
// 4 waves = 2 pairs x 32 rows; pair waves split c (128 each)
__global__ __launch_bounds__(256, 2) void k5c(float* __restrict__ wsF, const int* __restrict__ wsI) {
    const int Mv = wsI[II_M];
    const int i0 = blockIdx.x * RPBC;
    if (i0 >= Mv) return;
    __shared__ __align__(16) ushort sK[2][32 * CDIM];    // 2 x 16KB [j][c]
    __shared__ __align__(16) ushort sXT[2][CDIM * 32];   // 2 x 16KB paired rows [128R][128B]
    const int tid = threadIdx.x;
    const int wave = tid >> 6, lane = tid & 63;
    const int jl = lane & 31, g = lane >> 5;
    const int pair = wave >> 1, ch = wave & 1;
    const char* XnBb = (const char*)(wsF + OFF_XNB);
    const char* XTBb = (const char*)(wsF + OFF_XTB);
    const float* nflag = wsF + OFF_NFLAG;
    const int* anoIdx = wsI + II_ANOIDX;
    const int jc0 = blockIdx.y * JCH;
    const int ibase = i0 + pair * 32;
    const int myrow = ibase + jl;

    short8 qf[16];
    float rz, thr;
    {
        int ii = min(myrow, Mv - 1);
        int arow = anoIdx[ii];
#pragma unroll
        for (int kc = 0; kc < 16; ++kc)
            qf[kc] = *(const short8*)(XnBb + (size_t)arow * 512 + kc * 32 + g * 16);
        rz = 1.f / wsF[OFF_Z + ii];
        thr = wsF[OFF_THR + ii];
    }
    float den = 0.f;
    f32x16 oAcc[4];
#pragma unroll
    for (int ct = 0; ct < 4; ++ct)
#pragma unroll
        for (int r = 0; r < 16; ++r) oAcc[ct][r] = 0.f;

    auto stageK = [&](int buf, int j0) {
#pragma unroll
        for (int it = 0; it < 4; ++it) {
            int d = ((it * 256 + tid) << 4);
            int row = d >> 9;
            int srco = (d & ~511) | ((d & 511) ^ SWZ8(row));
            gld_lds16(XnBb + ((size_t)j0 << 9) + srco, (char*)sK[buf] + d);
        }
    };
    auto stageX = [&](int buf, int j0) {
#pragma unroll
        for (int it = 0; it < 4; ++it) {
            int d = ((it * 256 + tid) << 4);
            int R = d >> 7;
            int q = (d & 127) ^ SWZ8(R);
            int c = 2 * R + (q >> 6);
            gld_lds16(XTBb + (size_t)c * (P_TOT * 2) + ((size_t)j0 << 1) + (q & 63),
                      (char*)sXT[buf] + d);
        }
    };

    stageK(0, jc0);
    stageX(0, jc0);
    __syncthreads();
    int cur = 0;
    for (int js = 0; js < NJS; ++js) {
        int j0 = jc0 + js * 32;
        if (js + 1 < NJS) { stageK(cur ^ 1, j0 + 32); stageX(cur ^ 1, j0 + 32); }
        // QK: P^T tile, lane holds col i = jl, rows j per reg
        f32x16 acc;
#pragma unroll
        for (int r = 0; r < 16; ++r) acc[r] = 0.f;
#pragma unroll
        for (int kc = 0; kc < 16; ++kc) {
            int aoff = jl * 512 + ((kc * 32 + g * 16) ^ SWZ8(jl));
            short8 af = *(const short8*)((const char*)sK[cur] + aoff);
            acc = __builtin_amdgcn_mfma_f32_32x32x16_bf16(af, qf[kc], acc, 0, 0, 0);
        }
        // softmax-select in registers (i = jl fixed per lane)
        float nf = nflag[j0 + jl];
        unsigned um = (unsigned)__ballot(nf > 0.5f);
        float sw[16];
#pragma unroll
        for (int r = 0; r < 16; ++r) {
            int jr = (r & 3) + 8 * (r >> 2) + 4 * g;
            float w = ((um >> jr) & 1u) ? __expf(acc[r] - 1.f) * rz : 0.f;
            sw[r] = (w > thr) ? w : 0.f;
            den += sw[r];
        }
        // build PV A-frags per kk via pack + cross-half exchange
#pragma unroll
        for (int kk = 0; kk < 2; ++kk) {
            int s = 8 * kk;
            unsigned p0 = ((unsigned)f2bf(sw[s + 1]) << 16) | f2bf(sw[s + 0]);
            unsigned p1 = ((unsigned)f2bf(sw[s + 3]) << 16) | f2bf(sw[s + 2]);
            unsigned p2 = ((unsigned)f2bf(sw[s + 5]) << 16) | f2bf(sw[s + 4]);
            unsigned p3 = ((unsigned)f2bf(sw[s + 7]) << 16) | f2bf(sw[s + 6]);
            unsigned o0 = (unsigned)__shfl_xor((int)p0, 32);
            unsigned o1 = (unsigned)__shfl_xor((int)p1, 32);
            unsigned o2 = (unsigned)__shfl_xor((int)p2, 32);
            unsigned o3 = (unsigned)__shfl_xor((int)p3, 32);
            union { unsigned u[4]; short8 v; } fr;
            fr.u[0] = g ? o2 : p0;
            fr.u[1] = g ? o3 : p1;
            fr.u[2] = g ? p2 : o0;
            fr.u[3] = g ? p3 : o1;
#pragma unroll
            for (int ct = 0; ct < 4; ++ct) {
                int c = ch * 128 + ct * 32 + jl;
                int R = c >> 1;
                int off = (((c & 1) << 6) | (32 * kk + 16 * g)) ^ SWZ8(R);
                short8 bf = *(const short8*)((const char*)sXT[cur] + R * 128 + off);
                oAcc[ct] = __builtin_amdgcn_mfma_f32_32x32x16_bf16(fr.v, bf, oAcc[ct], 0, 0, 0);
            }
        }
        __syncthreads();
        cur ^= 1;
    }

    den += __shfl_xor(den, 32);
    if (ch == 0 && lane < 32 && myrow < Mv)
        atomicAdd(&wsF[OFF_DEN + myrow], den);
#pragma unroll
    for (int ct = 0; ct < 4; ++ct) {
        int col = ch * 128 + ct * 32 + jl;
#pragma unroll
        for (int r = 0; r < 16; ++r) {
            int row = ibase + (r & 3) + 8 * (r >> 2) + 4 * g;
            if (row < Mv)
                atomicAdd(&wsF[OFF_OUT + (size_t)row * CDIM + col], oAcc[ct][r]);
        }
    }
}

__global__ void k4d_final(float* __restrict__ out, const float* __restrict__ wsF,
                          const int* __restrict__ wsI) {
    int Mv = wsI[II_M];
    int i0 = blockIdx.x * TI;
    if (i0 >= Mv) return;
    int tid = threadIdx.x;
    int ii = tid >> 3, cg = tid & 7;
    int i = i0 + ii;
    if (i >= Mv) return;
    int p = wsI[II_ANOIDX + i];
    int b = p >> 10, n = p & 1023;
    float rden = 1.f / wsF[OFF_DEN + i];
    const float* go = wsF + OFF_OUT + (size_t)i * CDIM;
    float* op = out + (size_t)b * CDIM * NPIX + n;
#pragma unroll
    for (int cc = 0; cc < 32; ++cc) {
        int c = cc * 8 + cg;
        op[(size_t)c * NPIX] = go[c] * rden;
    }
}

extern "C" void kernel_launch(void* const* d_in, const int* in_sizes, int n_in,
                              void* d_out, int out_size, void* d_ws, size_t ws_size,
                              hipStream_t stream) {
    const float* f = (const float*)d_in[0];
    const float* center = (const float*)d_in[1];
    const float* Tc = (const float*)d_in[2];
    float* out = (float*)d_out;
    float* wsF = (float*)d_ws;
    int* wsI = (int*)(wsF + IOFF_BASE);

    hipMemsetAsync(wsF + OFF_Z, 0, (OFF_C2 + 64 - OFF_Z) * sizeof(float), stream);
    hipMemsetAsync(wsF + OFF_OUT, 0, (size_t)P_TOT * CDIM * sizeof(float), stream);
    hipMemsetAsync(wsI + II_M, 0, 2 * sizeof(int), stream);

    k0_prep<<<1, 256, 0, stream>>>(center, wsF);
    dim3 g1a(32, 4);
    k1a_dot<<<g1a, 256, 0, stream>>>(f, center, wsF + OFF_PART);
    k1b_min<<<32, 256, 0, stream>>>(Tc, wsF + OFF_C2, wsF + OFF_PART, wsF, wsI);
    dim3 g2(32, 8, 8), b2(32, 8);
    k2_convert<<<g2, b2, 0, stream>>>(f, wsF);
    k3_copy<<<512, 256, 0, stream>>>(f, out, wsF, wsI);
    dim3 g5a(P_TOT / RPBA, JSPA);
    k5a<<<g5a, 256, 0, stream>>>(wsF, wsI);
    k4b_thr<<<P_TOT / 256, 256, 0, stream>>>(wsF, wsI);
    dim3 g5c(P_TOT / RPBC, JSP);
    k5c<<<g5c, 256, 0, stream>>>(wsF, wsI);
    k4d_final<<<P_TOT / TI, 256, 0, stream>>>(out, wsF, wsI);
}